// Round 2
// baseline (8456.488 us; speedup 1.0000x reference)
//
#include <hip/hip_runtime.h>
#include <stdint.h>

#define T_ 1024

typedef float  floatx4 __attribute__((ext_vector_type(4)));
typedef short  shortx8 __attribute__((ext_vector_type(8)));
typedef unsigned long long u64;

__device__ __forceinline__ unsigned short f2bf(float f) {
  union { float f; unsigned u; } v; v.f = f;
  return (unsigned short)((v.u + 0x7FFFu + ((v.u >> 16) & 1u)) >> 16);
}

// 16B load that is coherent at agent scope (sc-bypass, no L2 inv needed)
__device__ __forceinline__ shortx8 ld16_agent(const unsigned short* p) {
  union { u64 q[2]; shortx8 v; } u;
  u.q[0] = __hip_atomic_load((const u64*)p,     __ATOMIC_RELAXED, __HIP_MEMORY_SCOPE_AGENT);
  u.q[1] = __hip_atomic_load(((const u64*)p)+1, __ATOMIC_RELAXED, __HIP_MEMORY_SCOPE_AGENT);
  return u.v;
}

// ---- prep: pack rows [W_hh | W_ih] to bf16, zero flags ----
__global__ void prep_kernel(const float* __restrict__ wih0, const float* __restrict__ whh0,
                            const float* __restrict__ wih1, const float* __restrict__ whh1,
                            unsigned short* __restrict__ wcat0, unsigned short* __restrict__ wcat1,
                            unsigned* __restrict__ f0, unsigned* __restrict__ f1) {
  long gid = (long)blockIdx.x * 256 + threadIdx.x;
  if (gid < 1024) f0[gid] = 0u;
  else if (gid < 2048) f1[gid - 1024] = 0u;
  const long n0 = 3072L * 1280 / 8;
  const long n1 = 3072L * 2048 / 8;
  union { unsigned short s[8]; uint4 v; } t;
  if (gid < n0) {
    long e = gid * 8; int row = (int)(e / 1280); int k = (int)(e % 1280);
    const float* src = (k < 1024) ? (whh0 + (long)row * 1024 + k)
                                  : (wih0 + (long)row * 256 + (k - 1024));
#pragma unroll
    for (int j = 0; j < 8; ++j) t.s[j] = f2bf(src[j]);
    *(uint4*)(wcat0 + e) = t.v;
  } else if (gid < n0 + n1) {
    long e = (gid - n0) * 8; int row = (int)(e / 2048); int k = (int)(e % 2048);
    const float* src = (k < 1024) ? (whh1 + (long)row * 1024 + k)
                                  : (wih1 + (long)row * 1024 + (k - 1024));
#pragma unroll
    for (int j = 0; j < 8; ++j) t.s[j] = f2bf(src[j]);
    *(uint4*)(wcat1 + e) = t.v;
  }
}

// ---- persistent GRU: 64 blocks/layer, 16 cols/block, weights resident, no fences ----
template<int L>
__device__ __forceinline__ void gru_body(int lb, int tid,
    const float* __restrict__ x,
    const unsigned short* __restrict__ wcat,
    const float* __restrict__ bihg, const float* __restrict__ bhhg,
    unsigned short* __restrict__ y0ring, unsigned short* __restrict__ h1ring,
    float* __restrict__ dout,
    unsigned* __restrict__ f0, unsigned* __restrict__ f1,
    float (*part)[8][4][272])
{
  constexpr int KW  = L ? 2048 : 1280;
  constexpr int KTX = L ? 4 : 1;
  const int cb = lb * 16;
  const int w  = tid >> 6;
  const int l  = tid & 63;
  const int lr = l & 15, lq = l >> 4;

  // B-fragments resident for the whole time loop; A and B use the SAME
  // (lq,elem)->k mapping so any intra-tile k-permutation cancels.
  shortx8 bfh[3][4];
  shortx8 bfx[3][KTX];
#pragma unroll
  for (int g = 0; g < 3; ++g) {
    const unsigned short* wr = wcat + (long)(g * 1024 + cb + lr) * KW;
#pragma unroll
    for (int kt = 0; kt < 4; ++kt)
      bfh[g][kt] = *(const shortx8*)(wr + w * 128 + kt * 32 + lq * 8);
    if constexpr (L == 0) {
      bfx[g][0] = *(const shortx8*)(wr + 1024 + w * 32 + lq * 8);
    } else {
#pragma unroll
      for (int kt = 0; kt < KTX; ++kt)
        bfx[g][kt] = *(const shortx8*)(wr + 1024 + w * 128 + kt * 32 + lq * 8);
    }
  }

  // gate-thread private state (tid < 256): biases + h_prev in registers
  const int gb = tid >> 4, gc = tid & 15;
  float bir = 0, biz = 0, bin = 0, bhr = 0, bhz = 0, bhn = 0, hp = 0;
  if (tid < 256) {
    bir = bihg[cb + gc];        bhr = bhhg[cb + gc];
    biz = bihg[1024 + cb + gc]; bhz = bhhg[1024 + cb + gc];
    bin = bihg[2048 + cb + gc]; bhn = bhhg[2048 + cb + gc];
  }

  unsigned* fown = L ? f1 : f0;
  unsigned* foth = L ? f0 : f1;
  const unsigned* pown = fown + (l << 4);   // 64B-strided slots, one per block
  const unsigned* poth = foth + (l << 4);
  unsigned* fslot = fown + (lb << 4);

  for (int t = 0; t < T_; ++t) {
    const int tgt_own = 4 * t;                        // own layer completed t-1
    const int tgt_oth = L ? 4 * (t + 1) : 4 * (t - 15); // L1: y0[t] ready; L0: ring slot freed
    for (;;) {
      int a = (int)__hip_atomic_load(pown, __ATOMIC_RELAXED, __HIP_MEMORY_SCOPE_AGENT);
      int b = (int)__hip_atomic_load(poth, __ATOMIC_RELAXED, __HIP_MEMORY_SCOPE_AGENT);
      if (__all(a >= tgt_own && b >= tgt_oth)) break;
    }
    asm volatile("" ::: "memory");

    // ---- A-fragments straight from exchange buffers (agent-coherent loads) ----
    floatx4 ar = {0.f, 0.f, 0.f, 0.f};
    floatx4 az = ar, anh = ar, anx = ar;
    shortx8 Ah[4], Ax[KTX];
    if (t > 0) {
      const unsigned short* hs = L
        ? (h1ring + (((t - 1) & 1) * 16 + lr) * 1024)
        : (y0ring + (((t - 1) & 15) * 16 + lr) * 1024);
#pragma unroll
      for (int kt = 0; kt < 4; ++kt)
        Ah[kt] = ld16_agent(hs + w * 128 + kt * 32 + lq * 8);
    }
    if constexpr (L == 1) {
      const unsigned short* xs = y0ring + ((t & 15) * 16 + lr) * 1024;
#pragma unroll
      for (int kt = 0; kt < 4; ++kt)
        Ax[kt] = ld16_agent(xs + w * 128 + kt * 32 + lq * 8);
    } else {
      const float* xs = x + ((long)lr * T_ + t) * 256 + w * 32 + lq * 8;
      float4 v0 = *(const float4*)xs;
      float4 v1 = *(const float4*)(xs + 4);
      union { unsigned short s[8]; shortx8 v; } u;
      u.s[0] = f2bf(v0.x); u.s[1] = f2bf(v0.y); u.s[2] = f2bf(v0.z); u.s[3] = f2bf(v0.w);
      u.s[4] = f2bf(v1.x); u.s[5] = f2bf(v1.y); u.s[6] = f2bf(v1.z); u.s[7] = f2bf(v1.w);
      Ax[0] = u.v;
    }

    if (t > 0) {
#pragma unroll
      for (int kt = 0; kt < 4; ++kt) {
        ar  = __builtin_amdgcn_mfma_f32_16x16x32_bf16(Ah[kt], bfh[0][kt], ar,  0, 0, 0);
        az  = __builtin_amdgcn_mfma_f32_16x16x32_bf16(Ah[kt], bfh[1][kt], az,  0, 0, 0);
        anh = __builtin_amdgcn_mfma_f32_16x16x32_bf16(Ah[kt], bfh[2][kt], anh, 0, 0, 0);
      }
    }
#pragma unroll
    for (int kt = 0; kt < KTX; ++kt) {
      ar  = __builtin_amdgcn_mfma_f32_16x16x32_bf16(Ax[kt], bfx[0][kt], ar,  0, 0, 0);
      az  = __builtin_amdgcn_mfma_f32_16x16x32_bf16(Ax[kt], bfx[1][kt], az,  0, 0, 0);
      anx = __builtin_amdgcn_mfma_f32_16x16x32_bf16(Ax[kt], bfx[2][kt], anx, 0, 0, 0);
    }

    // ---- cross-wave reduce via double-buffered LDS (one barrier per step) ----
    const int par = t & 1;
#pragma unroll
    for (int r4 = 0; r4 < 4; ++r4) {
      const int idx = (lq * 4 + r4) * 17 + lr;   // row=batch, col=hidden (m89 layout)
      part[par][w][0][idx] = ar[r4];
      part[par][w][1][idx] = az[r4];
      part[par][w][2][idx] = anh[r4];
      part[par][w][3][idx] = anx[r4];
    }
    __syncthreads();

    if (tid < 256) {
      const int idx = gb * 17 + gc;
      float sr = 0, sz = 0, snh = 0, snx = 0;
#pragma unroll
      for (int ww = 0; ww < 8; ++ww) {
        sr  += part[par][ww][0][idx];
        sz  += part[par][ww][1][idx];
        snh += part[par][ww][2][idx];
        snx += part[par][ww][3][idx];
      }
      float r = 1.f / (1.f + __expf(-(sr + bir + bhr)));
      float z = 1.f / (1.f + __expf(-(sz + biz + bhz)));
      float targ = snx + bin + r * (snh + bhn);
      float e2 = __expf(2.f * targ);
      float n = 1.f - 2.f / (e2 + 1.f);          // tanh
      float hn = (1.f - z) * n + z * hp;
      hp = hn;
      if (L == 1)
        dout[(long)gb * (T_ * 1024) + (long)t * 1024 + cb + gc] = hn;
      if (t == T_ - 1)
        dout[16777216L + (L ? 16384 : 0) + (long)gb * 1024 + cb + gc] = hn;
      // publish h (bf16, paired into 4B agent-scope stores)
      unsigned hv = f2bf(hn);
      unsigned ov = (unsigned)__shfl_xor((int)hv, 1);
      unsigned short* ring = L ? (h1ring + ((t & 1) * 16 + gb) * 1024)
                               : (y0ring + ((t & 15) * 16 + gb) * 1024);
      if ((gc & 1) == 0) {
        unsigned pv = hv | (ov << 16);
        __hip_atomic_store((unsigned*)(ring + cb + gc), pv,
                           __ATOMIC_RELAXED, __HIP_MEMORY_SCOPE_AGENT);
      }
      asm volatile("s_waitcnt vmcnt(0)");        // data visible before flag
      if (l == 0)
        __hip_atomic_fetch_add(fslot, 1u, __ATOMIC_RELAXED, __HIP_MEMORY_SCOPE_AGENT);
    }
  }
}

__global__ __launch_bounds__(512) void gru_kernel(
    const float* __restrict__ x,
    const unsigned short* __restrict__ wcat0, const unsigned short* __restrict__ wcat1,
    const float* __restrict__ bih0, const float* __restrict__ bhh0,
    const float* __restrict__ bih1, const float* __restrict__ bhh1,
    unsigned short* y0ring, unsigned short* h1ring, float* dout,
    unsigned* f0, unsigned* f1)
{
  __shared__ float part[2][8][4][272];   // 69,632 B double-buffered partials
  const int bid = blockIdx.x, tid = threadIdx.x;
  if (bid < 64)
    gru_body<0>(bid, tid, x, wcat0, bih0, bhh0, y0ring, h1ring, dout, f0, f1, part);
  else
    gru_body<1>(bid - 64, tid, x, wcat1, bih1, bhh1, y0ring, h1ring, dout, f0, f1, part);
}

extern "C" void kernel_launch(void* const* d_in, const int* in_sizes, int n_in,
                              void* d_out, int out_size, void* d_ws, size_t ws_size,
                              hipStream_t stream) {
  (void)in_sizes; (void)n_in; (void)out_size; (void)ws_size;
  const float* x    = (const float*)d_in[0];
  const float* wih0 = (const float*)d_in[2];
  const float* whh0 = (const float*)d_in[3];
  const float* bih0 = (const float*)d_in[4];
  const float* bhh0 = (const float*)d_in[5];
  const float* wih1 = (const float*)d_in[6];
  const float* whh1 = (const float*)d_in[7];
  const float* bih1 = (const float*)d_in[8];
  const float* bhh1 = (const float*)d_in[9];
  char* ws = (char*)d_ws;
  unsigned short* wcat0  = (unsigned short*)(ws + 0L);         //  7,864,320 B
  unsigned short* wcat1  = (unsigned short*)(ws + 7864320L);   // 12,582,912 B
  unsigned short* y0ring = (unsigned short*)(ws + 20447232L);  //    524,288 B (16 slots)
  unsigned short* h1ring = (unsigned short*)(ws + 20971520L);  //     65,536 B (2 slots)
  unsigned* f0 = (unsigned*)(ws + 21037056L);                  //      4,096 B
  unsigned* f1 = (unsigned*)(ws + 21041152L);                  //      4,096 B
  float* out = (float*)d_out;

  prep_kernel<<<4992, 256, 0, stream>>>(wih0, whh0, wih1, whh1, wcat0, wcat1, f0, f1);
  gru_kernel<<<128, 512, 0, stream>>>(x, wcat0, wcat1, bih0, bhh0, bih1, bhh1,
                                      y0ring, h1ring, out, f0, f1);
}